// Round 2
// baseline (974.495 us; speedup 1.0000x reference)
//
#include <hip/hip_runtime.h>
#include <stdint.h>

#define CANDS 32768
#define HID   1024
#define KDIM  4096
#define NREL  10

typedef __attribute__((ext_vector_type(8))) short bf16x8;   // 8 bf16 = 4 VGPRs
typedef __attribute__((ext_vector_type(4))) float f32x4;

__device__ __forceinline__ float bf2f(unsigned short u) {
  union { unsigned int i; float f; } v; v.i = ((unsigned int)u) << 16; return v.f;
}
__device__ __forceinline__ unsigned short f2bf(float f) {
  union { float f; unsigned int i; } v; v.f = f;
  unsigned int x = v.i;
  return (unsigned short)((x + 0x7FFFu + ((x >> 16) & 1u)) >> 16);  // RNE
}
// async global->LDS, 16B per lane. LDS dest must be wave-uniform base + lane*16.
__device__ __forceinline__ void async16(const void* g, void* l) {
  __builtin_amdgcn_global_load_lds(
      (const __attribute__((address_space(1))) unsigned int*)(uintptr_t)g,
      (__attribute__((address_space(3))) unsigned int*)(uintptr_t)l,
      16, 0, 0);
}

// ---------- kernel 1: W1 fp32 [4096][1024] -> W1T bf16 [1024][4096] ----------
__global__ void transpose_w1(const float* __restrict__ W1,
                             unsigned short* __restrict__ W1T) {
  __shared__ __align__(16) unsigned short tile[64][72];  // +8 pad breaks bank conflicts
  int bk = blockIdx.x;            // 64 tiles along K=4096
  int bn = blockIdx.y;            // 16 tiles along N=1024
  int t = threadIdx.x;            // 256
  int r = t >> 3, c8 = (t & 7) * 8;
  for (int i = 0; i < 2; ++i) {
    int rr = r + i * 32;
    const float4* src = (const float4*)(W1 + (size_t)(bk * 64 + rr) * HID + bn * 64 + c8);
    float4 v0 = src[0], v1 = src[1];
    tile[rr][c8 + 0] = f2bf(v0.x); tile[rr][c8 + 1] = f2bf(v0.y);
    tile[rr][c8 + 2] = f2bf(v0.z); tile[rr][c8 + 3] = f2bf(v0.w);
    tile[rr][c8 + 4] = f2bf(v1.x); tile[rr][c8 + 5] = f2bf(v1.y);
    tile[rr][c8 + 6] = f2bf(v1.z); tile[rr][c8 + 7] = f2bf(v1.w);
  }
  __syncthreads();
  for (int i = 0; i < 2; ++i) {
    int rr = r + i * 32;
    unsigned short tmp[8];
    for (int j = 0; j < 8; ++j) tmp[j] = tile[c8 + j][rr];
    ushort4* dst = (ushort4*)(W1T + (size_t)(bn * 64 + rr) * KDIM + bk * 64 + c8);
    dst[0] = *(ushort4*)&tmp[0];
    dst[1] = *(ushort4*)&tmp[4];
  }
}

// ----- kernel 2: gather fp32 emb + build feats [32768][4096] bf16 -----
__global__ void build_feats(const float* __restrict__ emb,
                            const int* __restrict__ sidx,
                            const int* __restrict__ didx,
                            unsigned short* __restrict__ feats) {
  int m = blockIdx.x;
  int t = threadIdx.x;  // 256 threads x 4 elems = 1024
  const float* srow = emb + (size_t)sidx[m] * HID;
  const float* drow = emb + (size_t)didx[m] * HID;
  float4 s4 = *(const float4*)(srow + t * 4);
  float4 d4 = *(const float4*)(drow + t * 4);
  unsigned short* o = feats + (size_t)m * KDIM;
  ushort4 sv, dv, av, pv;
  sv.x = f2bf(s4.x); sv.y = f2bf(s4.y); sv.z = f2bf(s4.z); sv.w = f2bf(s4.w);
  dv.x = f2bf(d4.x); dv.y = f2bf(d4.y); dv.z = f2bf(d4.z); dv.w = f2bf(d4.w);
  av.x = f2bf(fabsf(s4.x - d4.x)); av.y = f2bf(fabsf(s4.y - d4.y));
  av.z = f2bf(fabsf(s4.z - d4.z)); av.w = f2bf(fabsf(s4.w - d4.w));
  pv.x = f2bf(s4.x * d4.x); pv.y = f2bf(s4.y * d4.y);
  pv.z = f2bf(s4.z * d4.z); pv.w = f2bf(s4.w * d4.w);
  *(ushort4*)(o + t * 4)           = sv;
  *(ushort4*)(o + HID + t * 4)     = dv;
  *(ushort4*)(o + 2 * HID + t * 4) = av;
  *(ushort4*)(o + 3 * HID + t * 4) = pv;
}

// -------- kernel 3: GEMM1 feats[32768x4096] @ W1T^T -> GELU -> H[32768x1024] bf16 --------
#define BM 128
#define BN 128
#define BK 32
__global__ __launch_bounds__(256) void gemm1_gelu(
    const unsigned short* __restrict__ A,   // feats [M][4096] bf16
    const unsigned short* __restrict__ BT,  // W1T   [1024][4096] bf16
    const float* __restrict__ b1,           // [1024] fp32 (zeros)
    unsigned short* __restrict__ H) {       // [M][1024] bf16
  __shared__ __align__(16) unsigned short laA[BM * BK];   // [128][32] row-major, 8KB
  __shared__ __align__(16) unsigned short laB[BN * BK];
  int t = threadIdx.x;
  int lane = t & 63;
  int wave = t >> 6;
  int wrow = (wave >> 1) * 64, wcol = (wave & 1) * 64;
  int m0 = blockIdx.y * BM;
  int n0 = blockIdx.x * BN;
  int quad = lane >> 4, l16 = lane & 15;

  f32x4 acc[4][4] = {};

  int srow = t >> 2;              // 0..63
  int scol = (t & 3) * 8;         // element offset, 8 bf16 = 16B
  const unsigned short* gA0 = A  + (size_t)(m0 + srow) * KDIM + scol;
  const unsigned short* gA1 = A  + (size_t)(m0 + srow + 64) * KDIM + scol;
  const unsigned short* gB0 = BT + (size_t)(n0 + srow) * KDIM + scol;
  const unsigned short* gB1 = BT + (size_t)(n0 + srow + 64) * KDIM + scol;
  unsigned short* lA0 = &laA[srow * BK + scol];
  unsigned short* lA1 = &laA[(srow + 64) * BK + scol];
  unsigned short* lB0 = &laB[srow * BK + scol];
  unsigned short* lB1 = &laB[(srow + 64) * BK + scol];

  for (int kk = 0; kk < KDIM; kk += BK) {
    async16(gA0 + kk, lA0);
    async16(gA1 + kk, lA1);
    async16(gB0 + kk, lB0);
    async16(gB1 + kk, lB1);
    __syncthreads();   // compiler drains vmcnt before s_barrier
    bf16x8 af[4], bfr[4];
#pragma unroll
    for (int i = 0; i < 4; ++i)
      af[i] = *(const bf16x8*)&laA[(wrow + i * 16 + l16) * BK + quad * 8];
#pragma unroll
    for (int j = 0; j < 4; ++j)
      bfr[j] = *(const bf16x8*)&laB[(wcol + j * 16 + l16) * BK + quad * 8];
#pragma unroll
    for (int i = 0; i < 4; ++i)
#pragma unroll
      for (int j = 0; j < 4; ++j)
        acc[i][j] = __builtin_amdgcn_mfma_f32_16x16x32_bf16(af[i], bfr[j], acc[i][j], 0, 0, 0);
    __syncthreads();
  }
  // epilogue: bias + exact GELU, store bf16
#pragma unroll
  for (int j = 0; j < 4; ++j) {
    int n = n0 + wcol + j * 16 + l16;
    float bias = b1[n];
#pragma unroll
    for (int i = 0; i < 4; ++i) {
#pragma unroll
      for (int r = 0; r < 4; ++r) {
        int m = m0 + wrow + i * 16 + quad * 4 + r;
        float x = acc[i][j][r] + bias;
        float g = 0.5f * x * (1.0f + erff(x * 0.70710678118654752f));
        H[(size_t)m * HID + n] = f2bf(g);
      }
    }
  }
}

// ---- kernel 4: GEMM2 (H @ W2 + b2), log_softmax, fp32 logits store, loss partial ----
__global__ __launch_bounds__(256) void gemm2_loss(
    const unsigned short* __restrict__ H,    // [32768][1024] bf16
    const float* __restrict__ W2,            // [1024][10] fp32
    const float* __restrict__ b2,            // [10] fp32 (zeros)
    const int* __restrict__ labels,          // [32768]
    float* __restrict__ out,                 // out[0]=loss, out[1..]=logits fp32
    float* __restrict__ gacc) {
#define W2P 1032   // pitch in shorts: 2064B = 16B-aligned
  __shared__ __align__(16) unsigned short w2t[16 * W2P];
  __shared__ float lacc;
  int t = threadIdx.x;
  int lane = t & 63, wave = t >> 6;
  int quad = lane >> 4, l16 = lane & 15;
  if (t == 0) lacc = 0.0f;
  for (int k = t; k < HID; k += 256) {
    for (int j = 0; j < NREL; ++j) w2t[j * W2P + k] = f2bf(W2[(size_t)k * NREL + j]);
    for (int j = NREL; j < 16; ++j) w2t[j * W2P + k] = 0;
  }
  __syncthreads();

  int r0 = blockIdx.x * 64 + wave * 16;
  const unsigned short* hrow = H + (size_t)(r0 + l16) * HID;
  f32x4 acc = {};
#pragma unroll 8
  for (int s = 0; s < 32; ++s) {
    bf16x8 a = *(const bf16x8*)(hrow + s * 32 + quad * 8);
    bf16x8 b = *(const bf16x8*)&w2t[l16 * W2P + s * 32 + quad * 8];
    acc = __builtin_amdgcn_mfma_f32_16x16x32_bf16(a, b, acc, 0, 0, 0);
  }

  int col = l16;
  float bias = (col < NREL) ? b2[col] : 0.0f;
  float local = 0.0f;
#pragma unroll
  for (int r = 0; r < 4; ++r) {
    int row = r0 + quad * 4 + r;
    float x = acc[r] + bias;
    float v = (col < NREL) ? x : -1e30f;
    float mx = v;
    for (int d = 1; d < 16; d <<= 1) mx = fmaxf(mx, __shfl_xor(mx, d));
    float e = (col < NREL) ? expf(x - mx) : 0.0f;
    float se = e;
    for (int d = 1; d < 16; d <<= 1) se += __shfl_xor(se, d);
    float lse = mx + logf(se);
    if (col < NREL) {
      out[1 + (size_t)row * NREL + col] = x;
      if (labels[row] == col) local += (lse - x);   // -logp
    }
  }
  atomicAdd(&lacc, local);
  __syncthreads();
  if (t == 0) atomicAdd(gacc, lacc);
}

__global__ void finalize_loss(const float* __restrict__ gacc, float* __restrict__ out) {
  out[0] = *gacc * (1.0f / (float)CANDS);
}

extern "C" void kernel_launch(void* const* d_in, const int* in_sizes, int n_in,
                              void* d_out, int out_size, void* d_ws, size_t ws_size,
                              hipStream_t stream) {
  const float* emb    = (const float*)d_in[0];
  const int*   sidx   = (const int*)d_in[1];
  const int*   didx   = (const int*)d_in[2];
  const int*   labels = (const int*)d_in[3];
  const float* W1     = (const float*)d_in[4];
  const float* b1     = (const float*)d_in[5];
  const float* W2     = (const float*)d_in[6];
  const float* b2     = (const float*)d_in[7];
  float* out = (float*)d_out;

  char* ws = (char*)d_ws;
  float*          gacc  = (float*)ws;                                        // 4 B
  unsigned short* W1T   = (unsigned short*)(ws + 256);                       // 8 MB
  unsigned short* feats = (unsigned short*)(ws + 256 + 8388608);             // 256 MB
  unsigned short* H     = (unsigned short*)(ws + 256 + 8388608 + 268435456); // 64 MB

  hipMemsetAsync(gacc, 0, sizeof(float), stream);
  transpose_w1<<<dim3(64, 16), 256, 0, stream>>>(W1, W1T);
  build_feats<<<CANDS, 256, 0, stream>>>(emb, sidx, didx, feats);
  gemm1_gelu<<<dim3(HID / BN, CANDS / BM), 256, 0, stream>>>(feats, W1T, b1, H);
  gemm2_loss<<<CANDS / 64, 256, 0, stream>>>(H, W2, b2, labels, out, gacc);
  finalize_loss<<<1, 1, 0, stream>>>(gacc, out);
}

// Round 3
// 949.221 us; speedup vs baseline: 1.0266x; 1.0266x over previous
//
#include <hip/hip_runtime.h>
#include <stdint.h>

#define CANDS 32768
#define HID   1024
#define KDIM  4096
#define NREL  10

typedef __attribute__((ext_vector_type(8))) short bf16x8;   // 8 bf16 = 4 VGPRs
typedef __attribute__((ext_vector_type(4))) float f32x4;

__device__ __forceinline__ float bf2f(unsigned short u) {
  union { unsigned int i; float f; } v; v.i = ((unsigned int)u) << 16; return v.f;
}
__device__ __forceinline__ unsigned short f2bf(float f) {
  union { float f; unsigned int i; } v; v.f = f;
  unsigned int x = v.i;
  return (unsigned short)((x + 0x7FFFu + ((x >> 16) & 1u)) >> 16);  // RNE
}
// async global->LDS, 16B per lane. LDS dest must be wave-uniform base + lane*16.
__device__ __forceinline__ void async16(const void* g, void* l) {
  __builtin_amdgcn_global_load_lds(
      (const __attribute__((address_space(1))) unsigned int*)(uintptr_t)g,
      (__attribute__((address_space(3))) unsigned int*)(uintptr_t)l,
      16, 0, 0);
}

// ---------- kernel 1: W1 fp32 [4096][1024] -> W1T bf16 [1024][4096] ----------
__global__ void transpose_w1(const float* __restrict__ W1,
                             unsigned short* __restrict__ W1T) {
  __shared__ __align__(16) unsigned short tile[64][72];  // +8 pad breaks bank conflicts
  int bk = blockIdx.x;            // 64 tiles along K=4096
  int bn = blockIdx.y;            // 16 tiles along N=1024
  int t = threadIdx.x;            // 256
  int r = t >> 3, c8 = (t & 7) * 8;
  for (int i = 0; i < 2; ++i) {
    int rr = r + i * 32;
    const float4* src = (const float4*)(W1 + (size_t)(bk * 64 + rr) * HID + bn * 64 + c8);
    float4 v0 = src[0], v1 = src[1];
    tile[rr][c8 + 0] = f2bf(v0.x); tile[rr][c8 + 1] = f2bf(v0.y);
    tile[rr][c8 + 2] = f2bf(v0.z); tile[rr][c8 + 3] = f2bf(v0.w);
    tile[rr][c8 + 4] = f2bf(v1.x); tile[rr][c8 + 5] = f2bf(v1.y);
    tile[rr][c8 + 6] = f2bf(v1.z); tile[rr][c8 + 7] = f2bf(v1.w);
  }
  __syncthreads();
  for (int i = 0; i < 2; ++i) {
    int rr = r + i * 32;
    unsigned short tmp[8];
    for (int j = 0; j < 8; ++j) tmp[j] = tile[c8 + j][rr];
    ushort4* dst = (ushort4*)(W1T + (size_t)(bn * 64 + rr) * KDIM + bk * 64 + c8);
    dst[0] = *(ushort4*)&tmp[0];
    dst[1] = *(ushort4*)&tmp[4];
  }
}

// ----- kernel 2: gather fp32 emb + build feats [32768][4096] bf16 -----
// grid-stride: 2048 blocks x 16 rows each (was 32768 single-row blocks —
// dispatch-granularity bound).
__global__ __launch_bounds__(256) void build_feats(
    const float* __restrict__ emb,
    const int* __restrict__ sidx,
    const int* __restrict__ didx,
    unsigned short* __restrict__ feats) {
  int t = threadIdx.x;  // 256 threads x 4 elems = 1024 (one row per iter)
  for (int m = blockIdx.x; m < CANDS; m += gridDim.x) {
    const float* srow = emb + (size_t)sidx[m] * HID;
    const float* drow = emb + (size_t)didx[m] * HID;
    float4 s4 = *(const float4*)(srow + t * 4);
    float4 d4 = *(const float4*)(drow + t * 4);
    unsigned short* o = feats + (size_t)m * KDIM;
    ushort4 sv, dv, av, pv;
    sv.x = f2bf(s4.x); sv.y = f2bf(s4.y); sv.z = f2bf(s4.z); sv.w = f2bf(s4.w);
    dv.x = f2bf(d4.x); dv.y = f2bf(d4.y); dv.z = f2bf(d4.z); dv.w = f2bf(d4.w);
    av.x = f2bf(fabsf(s4.x - d4.x)); av.y = f2bf(fabsf(s4.y - d4.y));
    av.z = f2bf(fabsf(s4.z - d4.z)); av.w = f2bf(fabsf(s4.w - d4.w));
    pv.x = f2bf(s4.x * d4.x); pv.y = f2bf(s4.y * d4.y);
    pv.z = f2bf(s4.z * d4.z); pv.w = f2bf(s4.w * d4.w);
    *(ushort4*)(o + t * 4)           = sv;
    *(ushort4*)(o + HID + t * 4)     = dv;
    *(ushort4*)(o + 2 * HID + t * 4) = av;
    *(ushort4*)(o + 3 * HID + t * 4) = pv;
  }
}

// -------- kernel 3: GEMM1 feats[32768x4096] @ W1T^T -> GELU -> H[32768x1024] bf16 --------
// XCD-swizzled 1-D grid: the 8 N-tiles sharing one A-panel run as consecutive
// slots on the SAME XCD -> A-panel stays in that XCD's L2 (fetch A once).
#define BM 128
#define BN 128
#define BK 32
__global__ __launch_bounds__(256) void gemm1_gelu(
    const unsigned short* __restrict__ A,   // feats [M][4096] bf16
    const unsigned short* __restrict__ BT,  // W1T   [1024][4096] bf16
    const float* __restrict__ b1,           // [1024] fp32
    unsigned short* __restrict__ H) {       // [M][1024] bf16
  __shared__ __align__(16) unsigned short laA[BM * BK];   // 8KB
  __shared__ __align__(16) unsigned short laB[BN * BK];
  int bid = blockIdx.x;              // 2048 blocks
  int xcd = bid & 7;                 // round-robin XCD heuristic (perf-only)
  int s   = bid >> 3;                // XCD-local slot 0..255
  int m_tile = xcd * 32 + (s >> 3);  // 32 M-panels per XCD
  int n_tile = s & 7;                // n fastest within XCD -> A-panel reuse in L2
  int m0 = m_tile * BM;
  int n0 = n_tile * BN;

  int t = threadIdx.x;
  int lane = t & 63;
  int wave = t >> 6;
  int wrow = (wave >> 1) * 64, wcol = (wave & 1) * 64;
  int quad = lane >> 4, l16 = lane & 15;

  f32x4 acc[4][4] = {};

  int srow = t >> 2;              // 0..63
  int scol = (t & 3) * 8;         // element offset, 8 bf16 = 16B
  const unsigned short* gA0 = A  + (size_t)(m0 + srow) * KDIM + scol;
  const unsigned short* gA1 = A  + (size_t)(m0 + srow + 64) * KDIM + scol;
  const unsigned short* gB0 = BT + (size_t)(n0 + srow) * KDIM + scol;
  const unsigned short* gB1 = BT + (size_t)(n0 + srow + 64) * KDIM + scol;
  unsigned short* lA0 = &laA[srow * BK + scol];
  unsigned short* lA1 = &laA[(srow + 64) * BK + scol];
  unsigned short* lB0 = &laB[srow * BK + scol];
  unsigned short* lB1 = &laB[(srow + 64) * BK + scol];

  for (int kk = 0; kk < KDIM; kk += BK) {
    async16(gA0 + kk, lA0);
    async16(gA1 + kk, lA1);
    async16(gB0 + kk, lB0);
    async16(gB1 + kk, lB1);
    __syncthreads();   // compiler drains vmcnt before s_barrier
    bf16x8 af[4], bfr[4];
#pragma unroll
    for (int i = 0; i < 4; ++i)
      af[i] = *(const bf16x8*)&laA[(wrow + i * 16 + l16) * BK + quad * 8];
#pragma unroll
    for (int j = 0; j < 4; ++j)
      bfr[j] = *(const bf16x8*)&laB[(wcol + j * 16 + l16) * BK + quad * 8];
#pragma unroll
    for (int i = 0; i < 4; ++i)
#pragma unroll
      for (int j = 0; j < 4; ++j)
        acc[i][j] = __builtin_amdgcn_mfma_f32_16x16x32_bf16(af[i], bfr[j], acc[i][j], 0, 0, 0);
    __syncthreads();
  }
  // epilogue: bias + exact GELU, store bf16
#pragma unroll
  for (int j = 0; j < 4; ++j) {
    int n = n0 + wcol + j * 16 + l16;
    float bias = b1[n];
#pragma unroll
    for (int i = 0; i < 4; ++i) {
#pragma unroll
      for (int r = 0; r < 4; ++r) {
        int m = m0 + wrow + i * 16 + quad * 4 + r;
        float x = acc[i][j][r] + bias;
        float g = 0.5f * x * (1.0f + erff(x * 0.70710678118654752f));
        H[(size_t)m * HID + n] = f2bf(g);
      }
    }
  }
}

// ---- kernel 4: GEMM2 (H @ W2 + b2), log_softmax, fp32 logits store, loss partial ----
__global__ __launch_bounds__(256) void gemm2_loss(
    const unsigned short* __restrict__ H,    // [32768][1024] bf16
    const float* __restrict__ W2,            // [1024][10] fp32
    const float* __restrict__ b2,            // [10] fp32
    const int* __restrict__ labels,          // [32768]
    float* __restrict__ out,                 // out[0]=loss, out[1..]=logits fp32
    float* __restrict__ gacc) {
#define W2P 1032   // pitch in shorts: 2064B = 16B-aligned
  __shared__ __align__(16) unsigned short w2t[16 * W2P];
  __shared__ float lacc;
  int t = threadIdx.x;
  int lane = t & 63, wave = t >> 6;
  int quad = lane >> 4, l16 = lane & 15;
  if (t == 0) lacc = 0.0f;
  for (int k = t; k < HID; k += 256) {
    for (int j = 0; j < NREL; ++j) w2t[j * W2P + k] = f2bf(W2[(size_t)k * NREL + j]);
    for (int j = NREL; j < 16; ++j) w2t[j * W2P + k] = 0;
  }
  __syncthreads();

  int r0 = blockIdx.x * 64 + wave * 16;
  const unsigned short* hrow = H + (size_t)(r0 + l16) * HID;
  f32x4 acc = {};
#pragma unroll 8
  for (int s = 0; s < 32; ++s) {
    bf16x8 a = *(const bf16x8*)(hrow + s * 32 + quad * 8);
    bf16x8 b = *(const bf16x8*)&w2t[l16 * W2P + s * 32 + quad * 8];
    acc = __builtin_amdgcn_mfma_f32_16x16x32_bf16(a, b, acc, 0, 0, 0);
  }

  int col = l16;
  float bias = (col < NREL) ? b2[col] : 0.0f;
  float local = 0.0f;
#pragma unroll
  for (int r = 0; r < 4; ++r) {
    int row = r0 + quad * 4 + r;
    float x = acc[r] + bias;
    float v = (col < NREL) ? x : -1e30f;
    float mx = v;
    for (int d = 1; d < 16; d <<= 1) mx = fmaxf(mx, __shfl_xor(mx, d));
    float e = (col < NREL) ? expf(x - mx) : 0.0f;
    float se = e;
    for (int d = 1; d < 16; d <<= 1) se += __shfl_xor(se, d);
    float lse = mx + logf(se);
    if (col < NREL) {
      out[1 + (size_t)row * NREL + col] = x;
      if (labels[row] == col) local += (lse - x);   // -logp
    }
  }
  atomicAdd(&lacc, local);
  __syncthreads();
  if (t == 0) atomicAdd(gacc, lacc);
}

__global__ void finalize_loss(const float* __restrict__ gacc, float* __restrict__ out) {
  out[0] = *gacc * (1.0f / (float)CANDS);
}

extern "C" void kernel_launch(void* const* d_in, const int* in_sizes, int n_in,
                              void* d_out, int out_size, void* d_ws, size_t ws_size,
                              hipStream_t stream) {
  const float* emb    = (const float*)d_in[0];
  const int*   sidx   = (const int*)d_in[1];
  const int*   didx   = (const int*)d_in[2];
  const int*   labels = (const int*)d_in[3];
  const float* W1     = (const float*)d_in[4];
  const float* b1     = (const float*)d_in[5];
  const float* W2     = (const float*)d_in[6];
  const float* b2     = (const float*)d_in[7];
  float* out = (float*)d_out;

  char* ws = (char*)d_ws;
  float*          gacc  = (float*)ws;                                        // 4 B
  unsigned short* W1T   = (unsigned short*)(ws + 256);                       // 8 MB
  unsigned short* feats = (unsigned short*)(ws + 256 + 8388608);             // 256 MB
  unsigned short* H     = (unsigned short*)(ws + 256 + 8388608 + 268435456); // 64 MB

  hipMemsetAsync(gacc, 0, sizeof(float), stream);
  transpose_w1<<<dim3(64, 16), 256, 0, stream>>>(W1, W1T);
  build_feats<<<2048, 256, 0, stream>>>(emb, sidx, didx, feats);
  gemm1_gelu<<<2048, 256, 0, stream>>>(feats, W1T, b1, H);
  gemm2_loss<<<CANDS / 64, 256, 0, stream>>>(H, W2, b2, labels, out, gacc);
  finalize_loss<<<1, 1, 0, stream>>>(gacc, out);
}